// Round 11
// baseline (192.030 us; speedup 1.0000x reference)
//
#include <hip/hip_runtime.h>

// ---------------------------------------------------------------------------
// FasterMultiHeadAttention: B=2, S=2048, D=1024, H=16, HD=64  (fp32 in/out)
// R11 = R10 with transposed-C GEMM epilogues (operand-order swap = free C^T,
// same fragment reads):
//  - gemm_qkv: Q/K blocks (bn<16) compute C^T so r spans 4 consecutive hd ->
//    8 x b64 stores/thread (was 32 x b16). V blocks keep standard orientation
//    (b64 stores need r=token). Block-uniform branch.
//  - gemm_out: C^T everywhere -> 8 x float4 stores/thread (was 32 x dword).
// attn (R9 key-split static-max flash) and casts unchanged.
// ---------------------------------------------------------------------------

typedef __attribute__((ext_vector_type(8))) short bs8;     // 8 bf16 (4 VGPR)
typedef __attribute__((ext_vector_type(4))) short bs4;     // 4 bf16 (2 VGPR)
typedef __attribute__((ext_vector_type(4))) float f32x4;   // MFMA acc

__device__ __forceinline__ f32x4 MFMA16K16(bs4 a, bs4 b, f32x4 c) {
#if defined(__HIP_DEVICE_COMPILE__)
  return __builtin_amdgcn_mfma_f32_16x16x16bf16_1k(a, b, c, 0, 0, 0);
#else
  return c;  // host pass only type-checks; never executed
#endif
}

#define QSCALE 0.18033688011112042f  // (1/8) * log2(e)
#define MBOUND 24.0f                 // static softmax shift (scores |s| <~ 10)

// round-half-up fp32->bf16: error <= 0.5 ulp (same bound as RNE), 2 VALU ops
__device__ __forceinline__ unsigned short f2bf(float f) {
  union { float f; unsigned int u; } v; v.f = f;
  return (unsigned short)((v.u + 0x8000u) >> 16);
}

// pack two fp32 -> [lo16=bf16(a), hi16=bf16(b)] : 2 adds + 1 v_perm_b32
__device__ __forceinline__ unsigned int pkbf2(float a, float b) {
  union { float f; unsigned int u; } va, vb; va.f = a; vb.f = b;
#if defined(__HIP_DEVICE_COMPILE__)
  return __builtin_amdgcn_perm(vb.u + 0x8000u, va.u + 0x8000u, 0x07060302u);
#else
  return 0u;  // host pass only type-checks
#endif
}

// async global->LDS, 16B per lane. LDS dest = wave-uniform base + lane*16.
__device__ __forceinline__ void async16(const unsigned short* g, unsigned short* lds) {
  __builtin_amdgcn_global_load_lds(
      (const __attribute__((address_space(1))) unsigned int*)g,
      (__attribute__((address_space(3))) unsigned int*)lds, 16, 0, 0);
}

// Stage a 128-row x 64-col bf16 tile into LDS with chunk^(row&7) swizzle.
// 4-wave version: wave w covers rows [w*32, w*32+32).
__device__ __forceinline__ void stage_rows64(unsigned short* lds, const unsigned short* src,
                                             int ldk, int w, int l) {
#pragma unroll
  for (int i = 0; i < 4; ++i) {
    int row = (w * 4 + i) * 8 + (l >> 3);            // (row & 7) == (l>>3)
    int cg  = (l & 7) ^ (l >> 3);
    async16(src + (size_t)row * ldk + cg * 8, lds + (w * 4 + i) * 512);
  }
}

// 8-wave version: wave w covers rows [w*16, w*16+16). (Also stages a 64-row
// tile when called with w in 0..3.)
__device__ __forceinline__ void stage_rows64_8w(unsigned short* lds, const unsigned short* src,
                                                int ldk, int w, int l) {
#pragma unroll
  for (int i = 0; i < 2; ++i) {
    int row = (w * 2 + i) * 8 + (l >> 3);
    int cg  = (l & 7) ^ (l >> 3);
    async16(src + (size_t)row * ldk + cg * 8, lds + (w * 2 + i) * 512);
  }
}

// 64-row x 128-col Vt slice (row stride 2048), 8 waves, chunk^(row&15).
__device__ __forceinline__ void stage_vt_8w(unsigned short* lds, const unsigned short* vtb,
                                            int keyofs, int w, int l) {
#pragma unroll
  for (int i = 0; i < 2; ++i) {
    int row = (w * 2 + i) * 4 + (l >> 4);
    int cg = (l & 15) ^ (row & 15);
    async16(vtb + (size_t)row * 2048 + keyofs + cg * 8, lds + (w * 2 + i) * 512);
  }
}

// ---------------------------------------------------------------------------
__global__ __launch_bounds__(256) void cast_bf16_kernel(const float* __restrict__ src,
                                                        unsigned short* __restrict__ dst, int n) {
  int i = (blockIdx.x * 256 + threadIdx.x) * 8;
  if (i >= n) return;
  float4 a = *(const float4*)(src + i);
  float4 b = *(const float4*)(src + i + 4);
  union { bs8 v; unsigned short u[8]; } o;
  o.u[0] = f2bf(a.x); o.u[1] = f2bf(a.y); o.u[2] = f2bf(a.z); o.u[3] = f2bf(a.w);
  o.u[4] = f2bf(b.x); o.u[5] = f2bf(b.y); o.u[6] = f2bf(b.z); o.u[7] = f2bf(b.w);
  *(bs8*)(dst + i) = o.v;
}

// src [R][C] fp32  ->  dst [C][R] bf16
__global__ __launch_bounds__(256) void transpose_cast_kernel(const float* __restrict__ src,
                                                             unsigned short* __restrict__ dst,
                                                             int R, int C) {
  __shared__ unsigned short tile[64][73];
  int c0 = blockIdx.x * 64, r0 = blockIdx.y * 64;
  int t = threadIdx.x;
  int rl = t >> 2, cb = (t & 3) * 16;
  const float* p = src + (size_t)(r0 + rl) * C + c0 + cb;
#pragma unroll
  for (int j = 0; j < 16; j += 4) {
    float4 f = *(const float4*)(p + j);
    tile[rl][cb + j + 0] = f2bf(f.x);
    tile[rl][cb + j + 1] = f2bf(f.y);
    tile[rl][cb + j + 2] = f2bf(f.z);
    tile[rl][cb + j + 3] = f2bf(f.w);
  }
  __syncthreads();
  int cl = t >> 2, rb = (t & 3) * 16;
  unsigned short* q = dst + (size_t)(c0 + cl) * R + r0 + rb;
#pragma unroll
  for (int j = 0; j < 16; ++j) q[j] = tile[rb + j][cl];
}

// ---------------------------------------------------------------------------
// QKV GEMM: A [4096][1024] bf16, Bt [3072][1024] bf16. 128x128 block tile,
// 512 threads / 8 waves, wave tile 32 tokens x 64 features, BK=64.
// Q/K blocks (bn<16): transposed C (r spans hd) -> b64 stores to [bh][s][hd].
// V blocks (bn>=16): standard C (r spans s)  -> b64 stores to Vt [bh][hd][s]
// with half-chunk swap (bit-2 XOR of 4-aligned col base).
// ---------------------------------------------------------------------------
__global__ __launch_bounds__(512) void gemm_qkv_kernel(const unsigned short* __restrict__ A,
                                                       const unsigned short* __restrict__ Bt,
                                                       const float* __restrict__ bias,
                                                       unsigned short* __restrict__ qo,
                                                       unsigned short* __restrict__ ko,
                                                       unsigned short* __restrict__ vto) {
  __shared__ unsigned short As[128 * 64];
  __shared__ unsigned short Bs[128 * 64];
  int t = threadIdx.x, w = t >> 6, l = t & 63;
  int m16 = l & 15, q = l >> 4;
  int wm = w >> 1, wn = w & 1;          // wm 0..3 (32-token groups), wn 0..1 (64-feature)
  int bm = blockIdx.y, bn = blockIdx.x;
  bool vsec = (bn >= 16);               // block-uniform section select
  const unsigned short* Abase = A + (size_t)bm * 128 * 1024;
  const unsigned short* Bbase = Bt + (size_t)bn * 128 * 1024;
  f32x4 zero4 = {0.f, 0.f, 0.f, 0.f};
  f32x4 acc[2][4];
#pragma unroll
  for (int i = 0; i < 2; ++i)
#pragma unroll
    for (int j = 0; j < 4; ++j) acc[i][j] = zero4;
  for (int kt = 0; kt < 16; ++kt) {
    stage_rows64_8w(As, Abase + kt * 64, 1024, w, l);
    stage_rows64_8w(Bs, Bbase + kt * 64, 1024, w, l);
    __syncthreads();
#pragma unroll
    for (int ks = 0; ks < 2; ++ks) {
      bs8 af[2], bf[4];
#pragma unroll
      for (int mt = 0; mt < 2; ++mt) {
        int row = wm * 32 + mt * 16 + m16;
        int c = ks * 4 + q;
        af[mt] = *(const bs8*)&As[row * 64 + ((c ^ (row & 7)) * 8)];
      }
#pragma unroll
      for (int nt = 0; nt < 4; ++nt) {
        int row = wn * 64 + nt * 16 + m16;
        int c = ks * 4 + q;
        bf[nt] = *(const bs8*)&Bs[row * 64 + ((c ^ (row & 7)) * 8)];
      }
      if (vsec) {
        // standard: C[row=token][col=feature]
#pragma unroll
        for (int mt = 0; mt < 2; ++mt)
#pragma unroll
          for (int nt = 0; nt < 4; ++nt)
            acc[mt][nt] = __builtin_amdgcn_mfma_f32_16x16x32_bf16(af[mt], bf[nt],
                                                                  acc[mt][nt], 0, 0, 0);
      } else {
        // transposed: C[row=feature][col=token]
#pragma unroll
        for (int mt = 0; mt < 2; ++mt)
#pragma unroll
          for (int nt = 0; nt < 4; ++nt)
            acc[mt][nt] = __builtin_amdgcn_mfma_f32_16x16x32_bf16(bf[nt], af[mt],
                                                                  acc[mt][nt], 0, 0, 0);
      }
    }
    __syncthreads();
  }
  if (!vsec) {
    // ---- Q/K epilogue (transposed C): r spans 4 consecutive hd -> b64 store
#pragma unroll
    for (int nt = 0; nt < 4; ++nt) {
      int ng0 = bn * 128 + wn * 64 + nt * 16 + q * 4;
      float4 bb = *(const float4*)&bias[ng0];
      int sect = ng0 >> 10;             // 0=Q 1=K
      unsigned short* dst = sect ? ko : qo;
      float sc = sect ? 1.0f : QSCALE;
      int f0 = ng0 & 1023, h = f0 >> 6, hd0 = f0 & 63;
#pragma unroll
      for (int mt = 0; mt < 2; ++mt) {
        int mg = bm * 128 + wm * 32 + mt * 16 + m16;
        int b = mg >> 11, s = mg & 2047;
        union { bs4 v; unsigned short u[4]; } pv;
        pv.u[0] = f2bf((acc[mt][nt][0] + bb.x) * sc);
        pv.u[1] = f2bf((acc[mt][nt][1] + bb.y) * sc);
        pv.u[2] = f2bf((acc[mt][nt][2] + bb.z) * sc);
        pv.u[3] = f2bf((acc[mt][nt][3] + bb.w) * sc);
        *(bs4*)&dst[((size_t)(b * 16 + h) * 2048 + s) * 64 + hd0] = pv.v;
      }
    }
  } else {
    // ---- V epilogue (standard C): r spans 4 consecutive s -> b64 to Vt
#pragma unroll
    for (int nt = 0; nt < 4; ++nt) {
      int ng = bn * 128 + wn * 64 + nt * 16 + m16;
      float bb = bias[ng];
      int f = ng & 1023, h = f >> 6, hd = f & 63;
      int sw4 = (hd & 8) ? 4 : 0;
#pragma unroll
      for (int mt = 0; mt < 2; ++mt) {
        int mg0 = bm * 128 + wm * 32 + mt * 16 + q * 4;
        int b = mg0 >> 11, s0 = (mg0 & 2047) ^ sw4;
        union { bs4 v; unsigned short u[4]; } pv;
#pragma unroll
        for (int r = 0; r < 4; ++r) pv.u[r] = f2bf(acc[mt][nt][r] + bb);
        *(bs4*)&vto[((size_t)(b * 16 + h) * 64 + hd) * 2048 + s0] = pv.v;
      }
    }
  }
}

// ---------------------------------------------------------------------------
// Out GEMM: 64x128 block tile, 256 threads / 4 waves, wave tile 32x64 (2x2).
// Grid (8, 64) = 512 blocks -> 2 independent blocks/CU. Transposed C:
// r spans 4 consecutive output features -> float4 stores.
// ---------------------------------------------------------------------------
__global__ __launch_bounds__(256) void gemm_out_kernel(const unsigned short* __restrict__ A,
                                                       const unsigned short* __restrict__ Bt,
                                                       const float* __restrict__ bias,
                                                       float* __restrict__ out) {
  __shared__ unsigned short As[64 * 64];    // 8 KB
  __shared__ unsigned short Bs[128 * 64];   // 16 KB
  int t = threadIdx.x, w = t >> 6, l = t & 63;
  int m16 = l & 15, q = l >> 4;
  int wm = w >> 1, wn = w & 1;          // wm 0..1 (32-token), wn 0..1 (64-feature)
  int bm = blockIdx.y, bn = blockIdx.x;
  const unsigned short* Abase = A + (size_t)bm * 64 * 1024;
  const unsigned short* Bbase = Bt + (size_t)bn * 128 * 1024;
  f32x4 zero4 = {0.f, 0.f, 0.f, 0.f};
  f32x4 acc[2][4];
#pragma unroll
  for (int i = 0; i < 2; ++i)
#pragma unroll
    for (int j = 0; j < 4; ++j) acc[i][j] = zero4;
  for (int kt = 0; kt < 16; ++kt) {
    stage_rows64_8w(As, Abase + kt * 64, 1024, w, l);   // w 0..3 covers rows 0..63
    stage_rows64(Bs, Bbase + kt * 64, 1024, w, l);      // 4-wave, 128 rows
    __syncthreads();
#pragma unroll
    for (int ks = 0; ks < 2; ++ks) {
      bs8 af[2], bf[4];
#pragma unroll
      for (int mt = 0; mt < 2; ++mt) {
        int row = wm * 32 + mt * 16 + m16;
        int c = ks * 4 + q;
        af[mt] = *(const bs8*)&As[row * 64 + ((c ^ (row & 7)) * 8)];
      }
#pragma unroll
      for (int nt = 0; nt < 4; ++nt) {
        int row = wn * 64 + nt * 16 + m16;
        int c = ks * 4 + q;
        bf[nt] = *(const bs8*)&Bs[row * 64 + ((c ^ (row & 7)) * 8)];
      }
#pragma unroll
      for (int mt = 0; mt < 2; ++mt)
#pragma unroll
        for (int nt = 0; nt < 4; ++nt)
          acc[mt][nt] = __builtin_amdgcn_mfma_f32_16x16x32_bf16(bf[nt], af[mt],
                                                                acc[mt][nt], 0, 0, 0);
    }
    __syncthreads();
  }
#pragma unroll
  for (int nt = 0; nt < 4; ++nt) {
    int ng0 = bn * 128 + wn * 64 + nt * 16 + q * 4;
    float4 bb = *(const float4*)&bias[ng0];
#pragma unroll
    for (int mt = 0; mt < 2; ++mt) {
      int mg = bm * 64 + wm * 32 + mt * 16 + m16;
      float4 ov;
      ov.x = acc[mt][nt][0] + bb.x;
      ov.y = acc[mt][nt][1] + bb.y;
      ov.z = acc[mt][nt][2] + bb.z;
      ov.w = acc[mt][nt][3] + bb.w;
      *(float4*)&out[(size_t)mg * 1024 + ng0] = ov;
    }
  }
}

// ---------------------------------------------------------------------------
// Flash attention, S^T formulation, static-max softmax, key-split waves.
// grid = (16 q-tiles, 32 bh), 512 threads / 8 waves. Wave w: queries
// (w&3)*32..+31, keys (w>>2)*64..+63 of each 128-key tile. 16 iters,
// one barrier/iter, K/Vt double-buffered (64KB). Partial O/l summed across
// the two key-halves at the end via conflict-free LDS ([reg][wave][lane]).
// ---------------------------------------------------------------------------
__global__ __launch_bounds__(512, 4) void attn_kernel(const unsigned short* __restrict__ Q,
                                                      const unsigned short* __restrict__ K,
                                                      const unsigned short* __restrict__ Vt,
                                                      unsigned short* __restrict__ Aout) {
  __shared__ unsigned short Ks[2][128 * 64];    // 32 KB
  __shared__ unsigned short Vts[2][64 * 128];   // 32 KB
  int t = threadIdx.x, w = t >> 6, l = t & 63;
  int m16 = l & 15, q = l >> 4;
  int wq = w & 3, kh = w >> 2;                  // query group / key half
  int qt = blockIdx.x, bh = blockIdx.y;
  const unsigned short* qbase = Q + (size_t)bh * 2048 * 64 + (size_t)qt * 128 * 64;
  const unsigned short* kbase = K + (size_t)bh * 2048 * 64;
  const unsigned short* vtbase = Vt + (size_t)bh * 64 * 2048;

  // Q fragments: qf[mt][ks] = Q[wq*32+mt*16+m16][ks*32+q*8 ..+7]
  bs8 qf[2][2];
#pragma unroll
  for (int mt = 0; mt < 2; ++mt)
#pragma unroll
    for (int ks = 0; ks < 2; ++ks)
      qf[mt][ks] = *(const bs8*)(qbase + (size_t)(wq * 32 + mt * 16 + m16) * 64 + ks * 32 + q * 8);

  stage_rows64_8w(&Ks[0][0], kbase, 64, w, l);
  stage_vt_8w(&Vts[0][0], vtbase, 0, w, l);
  __syncthreads();

  f32x4 minit = {-MBOUND, -MBOUND, -MBOUND, -MBOUND};
  f32x4 zero4 = {0.f, 0.f, 0.f, 0.f};
  f32x4 o[2][4];
  float lsum[2] = {0.f, 0.f};
#pragma unroll
  for (int mt = 0; mt < 2; ++mt)
#pragma unroll
    for (int nh = 0; nh < 4; ++nh) o[mt][nh] = zero4;

  int vsw = (m16 >> 3) & 1;   // half-chunk unswizzle bit for vf reads

  for (int kt = 0; kt < 16; ++kt) {
    int buf = kt & 1;
    if (kt < 15) {
      stage_rows64_8w(&Ks[buf ^ 1][0], kbase + (size_t)(kt + 1) * 128 * 64, 64, w, l);
      stage_vt_8w(&Vts[buf ^ 1][0], vtbase, (kt + 1) * 128, w, l);
    }
    const unsigned short* Kb = &Ks[buf][0];
    const unsigned short* Vb = &Vts[buf][0];

    // ---- S^T tiles over this wave's 64 keys: sAcc[mt][nt], nt 0..3
    f32x4 sAcc[2][4];
#pragma unroll
    for (int mt = 0; mt < 2; ++mt)
#pragma unroll
      for (int nt = 0; nt < 4; ++nt) sAcc[mt][nt] = minit;
#pragma unroll
    for (int ks = 0; ks < 2; ++ks) {
      bs8 kf[4];
#pragma unroll
      for (int nt = 0; nt < 4; ++nt) {
        int row = kh * 64 + nt * 16 + m16;
        int c = ks * 4 + q;
        kf[nt] = *(const bs8*)&Kb[row * 64 + ((c ^ (row & 7)) * 8)];
      }
#pragma unroll
      for (int nt = 0; nt < 4; ++nt)
#pragma unroll
        for (int mt = 0; mt < 2; ++mt)
          sAcc[mt][nt] = __builtin_amdgcn_mfma_f32_16x16x32_bf16(kf[nt], qf[mt][ks],
                                                                 sAcc[mt][nt], 0, 0, 0);
    }

    // ---- p = exp2(s - 24), lane-local partial sums
#pragma unroll
    for (int mt = 0; mt < 2; ++mt) {
      float rs = 0.f;
#pragma unroll
      for (int nt = 0; nt < 4; ++nt)
#pragma unroll
        for (int r = 0; r < 4; ++r) {
          float p = __builtin_amdgcn_exp2f(sAcc[mt][nt][r]);
          sAcc[mt][nt][r] = p;
          rs += p;
        }
      lsum[mt] += rs;
    }

    // ---- partial O^T += V^T(key half) . P, straight from registers
#pragma unroll
    for (int nt = 0; nt < 4; ++nt) {
      bs4 vf[4];
#pragma unroll
      for (int nh = 0; nh < 4; ++nh) {
        int vrow = nh * 16 + m16;
        int chunk = kh * 8 + nt * 2 + (q >> 1);
        int within = ((q & 1) ^ vsw) * 4;          // matches Vt half-chunk swap
        vf[nh] = *(const bs4*)&Vb[vrow * 128 + ((chunk ^ (vrow & 15)) * 8) + within];
      }
#pragma unroll
      for (int mt = 0; mt < 2; ++mt) {
        union { bs4 v; unsigned int u[2]; } pf;
        pf.u[0] = pkbf2(sAcc[mt][nt][0], sAcc[mt][nt][1]);
        pf.u[1] = pkbf2(sAcc[mt][nt][2], sAcc[mt][nt][3]);
#pragma unroll
        for (int nh = 0; nh < 4; ++nh)
          o[mt][nh] = MFMA16K16(vf[nh], pf.v, o[mt][nh]);
      }
    }
    __syncthreads();
  }

  // ---- cross-key-half combine. Layout [reg][wave][lane]: lane stride 16B
  // for f32x4 -> conflict-free. Waves 4-7 publish, waves 0-3 add + write.
  float* ored = (float*)&Ks[0][0];    // 8 regs * 256 threads * 4 = 32 KB
  float* lred = (float*)&Vts[0][0];   // 2 * 256 floats = 2 KB
  if (w >= 4) {
#pragma unroll
    for (int mt = 0; mt < 2; ++mt)
#pragma unroll
      for (int nh = 0; nh < 4; ++nh)
        *(f32x4*)&ored[((mt * 4 + nh) * 256 + wq * 64 + l) * 4] = o[mt][nh];
    lred[0 * 256 + wq * 64 + l] = lsum[0];
    lred[1 * 256 + wq * 64 + l] = lsum[1];
  }
  __syncthreads();
  if (w < 4) {
#pragma unroll
    for (int mt = 0; mt < 2; ++mt)
#pragma unroll
      for (int nh = 0; nh < 4; ++nh) {
        f32x4 part = *(const f32x4*)&ored[((mt * 4 + nh) * 256 + wq * 64 + l) * 4];
#pragma unroll
        for (int r = 0; r < 4; ++r) o[mt][nh][r] += part[r];
      }
    lsum[0] += lred[0 * 256 + wq * 64 + l];
    lsum[1] += lred[1 * 256 + wq * 64 + l];

    int b = bh >> 4, h = bh & 15;
#pragma unroll
    for (int mt = 0; mt < 2; ++mt) {
      float l0 = lsum[mt];
      l0 += __shfl_xor(l0, 16);
      l0 += __shfl_xor(l0, 32);
      float inv = 1.0f / l0;
      int s = qt * 128 + wq * 32 + mt * 16 + m16;
#pragma unroll
      for (int nh = 0; nh < 4; ++nh)
#pragma unroll
        for (int r = 0; r < 4; ++r) {
          int hd = nh * 16 + q * 4 + r;
          Aout[((size_t)(b * 2048 + s)) * 1024 + h * 64 + hd] = f2bf(o[mt][nh][r] * inv);
        }
    }
  }
}

// ---------------------------------------------------------------------------
extern "C" void kernel_launch(void* const* d_in, const int* in_sizes, int n_in,
                              void* d_out, int out_size, void* d_ws, size_t ws_size,
                              hipStream_t stream) {
  const float* x     = (const float*)d_in[0];   // [2,2048,1024]
  const float* w_qkv = (const float*)d_in[1];   // [1024,3072]
  const float* b_qkv = (const float*)d_in[2];   // [3072]
  const float* w_out = (const float*)d_in[3];   // [1024,1024]
  const float* b_out = (const float*)d_in[4];   // [1024]
  float* out = (float*)d_out;                   // [2,2048,1024] fp32

  char* ws = (char*)d_ws;                       // needs 48 MB
  unsigned short* xb    = (unsigned short*)(ws);                     // 8 MB
  unsigned short* wt1   = (unsigned short*)(ws + (8u << 20));        // 6 MB
  unsigned short* wt2   = (unsigned short*)(ws + (14u << 20));       // 2 MB
  unsigned short* qb    = (unsigned short*)(ws + (16u << 20));       // 8 MB
  unsigned short* kb    = (unsigned short*)(ws + (24u << 20));       // 8 MB
  unsigned short* vtb   = (unsigned short*)(ws + (32u << 20));       // 8 MB
  unsigned short* attnb = (unsigned short*)(ws + (40u << 20));       // 8 MB

  cast_bf16_kernel<<<2048, 256, 0, stream>>>(x, xb, 4194304);
  transpose_cast_kernel<<<dim3(48, 16), 256, 0, stream>>>(w_qkv, wt1, 1024, 3072);
  transpose_cast_kernel<<<dim3(16, 16), 256, 0, stream>>>(w_out, wt2, 1024, 1024);
  gemm_qkv_kernel<<<dim3(24, 32), 512, 0, stream>>>(xb, wt1, b_qkv, qb, kb, vtb);
  attn_kernel<<<dim3(16, 32), 512, 0, stream>>>(qb, kb, vtb, attnb);
  gemm_out_kernel<<<dim3(8, 64), 256, 0, stream>>>(attnb, wt2, b_out, out);
}

// Round 12
// 188.838 us; speedup vs baseline: 1.0169x; 1.0169x over previous
//
#include <hip/hip_runtime.h>

// ---------------------------------------------------------------------------
// FasterMultiHeadAttention: B=2, S=2048, D=1024, H=16, HD=64  (fp32 in/out)
// R12 = R11 with:
//  - gemm_qkv reverted to the measured-874TF m97 structure: 256 thr / 4
//    waves, 64x64 wave tile, 4x4 acc (2x MFMA per LDS fragment read vs R11's
//    8-wave 2x4). C^T epilogue for Q/K (b64 stores), standard-C V -> Vt.
//  - cast + both weight transposes fused into ONE launch (block-range
//    branch): 2 fewer launch gaps, memory-bound jobs overlap across CUs.
// attn (R9 key-split static-max flash) and gemm_out (R11) unchanged.
// ---------------------------------------------------------------------------

typedef __attribute__((ext_vector_type(8))) short bs8;     // 8 bf16 (4 VGPR)
typedef __attribute__((ext_vector_type(4))) short bs4;     // 4 bf16 (2 VGPR)
typedef __attribute__((ext_vector_type(4))) float f32x4;   // MFMA acc

__device__ __forceinline__ f32x4 MFMA16K16(bs4 a, bs4 b, f32x4 c) {
#if defined(__HIP_DEVICE_COMPILE__)
  return __builtin_amdgcn_mfma_f32_16x16x16bf16_1k(a, b, c, 0, 0, 0);
#else
  return c;  // host pass only type-checks; never executed
#endif
}

#define QSCALE 0.18033688011112042f  // (1/8) * log2(e)
#define MBOUND 24.0f                 // static softmax shift (scores |s| <~ 10)

// round-half-up fp32->bf16: error <= 0.5 ulp (same bound as RNE), 2 VALU ops
__device__ __forceinline__ unsigned short f2bf(float f) {
  union { float f; unsigned int u; } v; v.f = f;
  return (unsigned short)((v.u + 0x8000u) >> 16);
}

// pack two fp32 -> [lo16=bf16(a), hi16=bf16(b)] : 2 adds + 1 v_perm_b32
__device__ __forceinline__ unsigned int pkbf2(float a, float b) {
  union { float f; unsigned int u; } va, vb; va.f = a; vb.f = b;
#if defined(__HIP_DEVICE_COMPILE__)
  return __builtin_amdgcn_perm(vb.u + 0x8000u, va.u + 0x8000u, 0x07060302u);
#else
  return 0u;  // host pass only type-checks
#endif
}

// async global->LDS, 16B per lane. LDS dest = wave-uniform base + lane*16.
__device__ __forceinline__ void async16(const unsigned short* g, unsigned short* lds) {
  __builtin_amdgcn_global_load_lds(
      (const __attribute__((address_space(1))) unsigned int*)g,
      (__attribute__((address_space(3))) unsigned int*)lds, 16, 0, 0);
}

// Stage a 128-row x 64-col bf16 tile into LDS with chunk^(row&7) swizzle.
// 4-wave version: wave w covers rows [w*32, w*32+32).
__device__ __forceinline__ void stage_rows64(unsigned short* lds, const unsigned short* src,
                                             int ldk, int w, int l) {
#pragma unroll
  for (int i = 0; i < 4; ++i) {
    int row = (w * 4 + i) * 8 + (l >> 3);            // (row & 7) == (l>>3)
    int cg  = (l & 7) ^ (l >> 3);
    async16(src + (size_t)row * ldk + cg * 8, lds + (w * 4 + i) * 512);
  }
}

// 8-wave version: wave w covers rows [w*16, w*16+16). (Also stages a 64-row
// tile when called with w in 0..3.)
__device__ __forceinline__ void stage_rows64_8w(unsigned short* lds, const unsigned short* src,
                                                int ldk, int w, int l) {
#pragma unroll
  for (int i = 0; i < 2; ++i) {
    int row = (w * 2 + i) * 8 + (l >> 3);
    int cg  = (l & 7) ^ (l >> 3);
    async16(src + (size_t)row * ldk + cg * 8, lds + (w * 2 + i) * 512);
  }
}

// 64-row x 128-col Vt slice (row stride 2048), 8 waves, chunk^(row&15).
__device__ __forceinline__ void stage_vt_8w(unsigned short* lds, const unsigned short* vtb,
                                            int keyofs, int w, int l) {
#pragma unroll
  for (int i = 0; i < 2; ++i) {
    int row = (w * 2 + i) * 4 + (l >> 4);
    int cg = (l & 15) ^ (row & 15);
    async16(vtb + (size_t)row * 2048 + keyofs + cg * 8, lds + (w * 2 + i) * 512);
  }
}

// ---------------------------------------------------------------------------
// Fused prep: blocks [0,2048): cast x -> bf16; [2048,2816): transpose w_qkv;
// [2816,3072): transpose w_out. One launch, jobs overlap across CUs.
// ---------------------------------------------------------------------------
__device__ __forceinline__ void transpose_cast_body(const float* __restrict__ src,
                                                    unsigned short* __restrict__ dst,
                                                    int R, int C, int bx, int by, int t) {
  __shared__ unsigned short tile[64][73];
  int c0 = bx * 64, r0 = by * 64;
  int rl = t >> 2, cb = (t & 3) * 16;
  const float* p = src + (size_t)(r0 + rl) * C + c0 + cb;
#pragma unroll
  for (int j = 0; j < 16; j += 4) {
    float4 f = *(const float4*)(p + j);
    tile[rl][cb + j + 0] = f2bf(f.x);
    tile[rl][cb + j + 1] = f2bf(f.y);
    tile[rl][cb + j + 2] = f2bf(f.z);
    tile[rl][cb + j + 3] = f2bf(f.w);
  }
  __syncthreads();
  int cl = t >> 2, rb = (t & 3) * 16;
  unsigned short* q = dst + (size_t)(c0 + cl) * R + r0 + rb;
#pragma unroll
  for (int j = 0; j < 16; ++j) q[j] = tile[rb + j][cl];
}

__global__ __launch_bounds__(256) void prep_kernel(const float* __restrict__ x,
                                                   unsigned short* __restrict__ xb,
                                                   const float* __restrict__ w_qkv,
                                                   unsigned short* __restrict__ wt1,
                                                   const float* __restrict__ w_out,
                                                   unsigned short* __restrict__ wt2) {
  int blk = blockIdx.x, t = threadIdx.x;
  if (blk < 2048) {
    int i = (blk * 256 + t) * 8;
    float4 a = *(const float4*)(x + i);
    float4 b = *(const float4*)(x + i + 4);
    union { bs8 v; unsigned short u[8]; } o;
    o.u[0] = f2bf(a.x); o.u[1] = f2bf(a.y); o.u[2] = f2bf(a.z); o.u[3] = f2bf(a.w);
    o.u[4] = f2bf(b.x); o.u[5] = f2bf(b.y); o.u[6] = f2bf(b.z); o.u[7] = f2bf(b.w);
    *(bs8*)(xb + i) = o.v;
  } else if (blk < 2816) {
    int i = blk - 2048;                       // 768 blocks = 48 x 16
    transpose_cast_body(w_qkv, wt1, 1024, 3072, i % 48, i / 48, t);
  } else {
    int i = blk - 2816;                       // 256 blocks = 16 x 16
    transpose_cast_body(w_out, wt2, 1024, 1024, i % 16, i / 16, t);
  }
}

// ---------------------------------------------------------------------------
// QKV GEMM (m97 structure): A [4096][1024] bf16, Bt [3072][1024] bf16.
// 128x128 block tile, 256 threads / 4 waves, wave tile 64x64, 4x4 acc, BK=64.
// Q/K blocks (bn<16): transposed C (r spans hd) -> b64 stores to [bh][s][hd].
// V blocks (bn>=16): standard C (r spans s)  -> b64 stores to Vt [bh][hd][s]
// with half-chunk swap (bit-2 XOR of 4-aligned col base).
// ---------------------------------------------------------------------------
__global__ __launch_bounds__(256) void gemm_qkv_kernel(const unsigned short* __restrict__ A,
                                                       const unsigned short* __restrict__ Bt,
                                                       const float* __restrict__ bias,
                                                       unsigned short* __restrict__ qo,
                                                       unsigned short* __restrict__ ko,
                                                       unsigned short* __restrict__ vto) {
  __shared__ unsigned short As[128 * 64];
  __shared__ unsigned short Bs[128 * 64];
  int t = threadIdx.x, w = t >> 6, l = t & 63;
  int m16 = l & 15, q = l >> 4;
  int wm = w >> 1, wn = w & 1;          // 64-token / 64-feature wave tile
  int bm = blockIdx.y, bn = blockIdx.x;
  bool vsec = (bn >= 16);               // block-uniform section select
  const unsigned short* Abase = A + (size_t)bm * 128 * 1024;
  const unsigned short* Bbase = Bt + (size_t)bn * 128 * 1024;
  f32x4 zero4 = {0.f, 0.f, 0.f, 0.f};
  f32x4 acc[4][4];
#pragma unroll
  for (int i = 0; i < 4; ++i)
#pragma unroll
    for (int j = 0; j < 4; ++j) acc[i][j] = zero4;
  for (int kt = 0; kt < 16; ++kt) {
    stage_rows64(As, Abase + kt * 64, 1024, w, l);
    stage_rows64(Bs, Bbase + kt * 64, 1024, w, l);
    __syncthreads();
#pragma unroll
    for (int ks = 0; ks < 2; ++ks) {
      bs8 af[4], bf[4];
#pragma unroll
      for (int mt = 0; mt < 4; ++mt) {
        int row = wm * 64 + mt * 16 + m16;
        int c = ks * 4 + q;
        af[mt] = *(const bs8*)&As[row * 64 + ((c ^ (row & 7)) * 8)];
      }
#pragma unroll
      for (int nt = 0; nt < 4; ++nt) {
        int row = wn * 64 + nt * 16 + m16;
        int c = ks * 4 + q;
        bf[nt] = *(const bs8*)&Bs[row * 64 + ((c ^ (row & 7)) * 8)];
      }
      if (vsec) {
        // standard: C[row=token][col=feature]
#pragma unroll
        for (int mt = 0; mt < 4; ++mt)
#pragma unroll
          for (int nt = 0; nt < 4; ++nt)
            acc[mt][nt] = __builtin_amdgcn_mfma_f32_16x16x32_bf16(af[mt], bf[nt],
                                                                  acc[mt][nt], 0, 0, 0);
      } else {
        // transposed: C[row=feature][col=token]
#pragma unroll
        for (int mt = 0; mt < 4; ++mt)
#pragma unroll
          for (int nt = 0; nt < 4; ++nt)
            acc[mt][nt] = __builtin_amdgcn_mfma_f32_16x16x32_bf16(bf[nt], af[mt],
                                                                  acc[mt][nt], 0, 0, 0);
      }
    }
    __syncthreads();
  }
  if (!vsec) {
    // ---- Q/K epilogue (transposed C): r spans 4 consecutive hd -> b64 store
#pragma unroll
    for (int nt = 0; nt < 4; ++nt) {
      int ng0 = bn * 128 + wn * 64 + nt * 16 + q * 4;
      float4 bb = *(const float4*)&bias[ng0];
      int sect = ng0 >> 10;             // 0=Q 1=K
      unsigned short* dst = sect ? ko : qo;
      float sc = sect ? 1.0f : QSCALE;
      int f0 = ng0 & 1023, h = f0 >> 6, hd0 = f0 & 63;
#pragma unroll
      for (int mt = 0; mt < 4; ++mt) {
        int mg = bm * 128 + wm * 64 + mt * 16 + m16;
        int b = mg >> 11, s = mg & 2047;
        union { bs4 v; unsigned short u[4]; } pv;
        pv.u[0] = f2bf((acc[mt][nt][0] + bb.x) * sc);
        pv.u[1] = f2bf((acc[mt][nt][1] + bb.y) * sc);
        pv.u[2] = f2bf((acc[mt][nt][2] + bb.z) * sc);
        pv.u[3] = f2bf((acc[mt][nt][3] + bb.w) * sc);
        *(bs4*)&dst[((size_t)(b * 16 + h) * 2048 + s) * 64 + hd0] = pv.v;
      }
    }
  } else {
    // ---- V epilogue (standard C): r spans 4 consecutive s -> b64 to Vt
#pragma unroll
    for (int nt = 0; nt < 4; ++nt) {
      int ng = bn * 128 + wn * 64 + nt * 16 + m16;
      float bb = bias[ng];
      int f = ng & 1023, h = f >> 6, hd = f & 63;
      int sw4 = (hd & 8) ? 4 : 0;
#pragma unroll
      for (int mt = 0; mt < 4; ++mt) {
        int mg0 = bm * 128 + wm * 64 + mt * 16 + q * 4;
        int b = mg0 >> 11, s0 = (mg0 & 2047) ^ sw4;
        union { bs4 v; unsigned short u[4]; } pv;
#pragma unroll
        for (int r = 0; r < 4; ++r) pv.u[r] = f2bf(acc[mt][nt][r] + bb);
        *(bs4*)&vto[((size_t)(b * 16 + h) * 64 + hd) * 2048 + s0] = pv.v;
      }
    }
  }
}

// ---------------------------------------------------------------------------
// Out GEMM: 64x128 block tile, 256 threads / 4 waves, wave tile 32x64 (2x2).
// Grid (8, 64) = 512 blocks -> 2 independent blocks/CU. Transposed C:
// r spans 4 consecutive output features -> float4 stores.
// ---------------------------------------------------------------------------
__global__ __launch_bounds__(256) void gemm_out_kernel(const unsigned short* __restrict__ A,
                                                       const unsigned short* __restrict__ Bt,
                                                       const float* __restrict__ bias,
                                                       float* __restrict__ out) {
  __shared__ unsigned short As[64 * 64];    // 8 KB
  __shared__ unsigned short Bs[128 * 64];   // 16 KB
  int t = threadIdx.x, w = t >> 6, l = t & 63;
  int m16 = l & 15, q = l >> 4;
  int wm = w >> 1, wn = w & 1;          // wm 0..1 (32-token), wn 0..1 (64-feature)
  int bm = blockIdx.y, bn = blockIdx.x;
  const unsigned short* Abase = A + (size_t)bm * 64 * 1024;
  const unsigned short* Bbase = Bt + (size_t)bn * 128 * 1024;
  f32x4 zero4 = {0.f, 0.f, 0.f, 0.f};
  f32x4 acc[2][4];
#pragma unroll
  for (int i = 0; i < 2; ++i)
#pragma unroll
    for (int j = 0; j < 4; ++j) acc[i][j] = zero4;
  for (int kt = 0; kt < 16; ++kt) {
    stage_rows64_8w(As, Abase + kt * 64, 1024, w, l);   // w 0..3 covers rows 0..63
    stage_rows64(Bs, Bbase + kt * 64, 1024, w, l);      // 4-wave, 128 rows
    __syncthreads();
#pragma unroll
    for (int ks = 0; ks < 2; ++ks) {
      bs8 af[2], bf[4];
#pragma unroll
      for (int mt = 0; mt < 2; ++mt) {
        int row = wm * 32 + mt * 16 + m16;
        int c = ks * 4 + q;
        af[mt] = *(const bs8*)&As[row * 64 + ((c ^ (row & 7)) * 8)];
      }
#pragma unroll
      for (int nt = 0; nt < 4; ++nt) {
        int row = wn * 64 + nt * 16 + m16;
        int c = ks * 4 + q;
        bf[nt] = *(const bs8*)&Bs[row * 64 + ((c ^ (row & 7)) * 8)];
      }
#pragma unroll
      for (int mt = 0; mt < 2; ++mt)
#pragma unroll
        for (int nt = 0; nt < 4; ++nt)
          acc[mt][nt] = __builtin_amdgcn_mfma_f32_16x16x32_bf16(bf[nt], af[mt],
                                                                acc[mt][nt], 0, 0, 0);
    }
    __syncthreads();
  }
#pragma unroll
  for (int nt = 0; nt < 4; ++nt) {
    int ng0 = bn * 128 + wn * 64 + nt * 16 + q * 4;
    float4 bb = *(const float4*)&bias[ng0];
#pragma unroll
    for (int mt = 0; mt < 2; ++mt) {
      int mg = bm * 64 + wm * 32 + mt * 16 + m16;
      float4 ov;
      ov.x = acc[mt][nt][0] + bb.x;
      ov.y = acc[mt][nt][1] + bb.y;
      ov.z = acc[mt][nt][2] + bb.z;
      ov.w = acc[mt][nt][3] + bb.w;
      *(float4*)&out[(size_t)mg * 1024 + ng0] = ov;
    }
  }
}

// ---------------------------------------------------------------------------
// Flash attention, S^T formulation, static-max softmax, key-split waves.
// grid = (16 q-tiles, 32 bh), 512 threads / 8 waves. Wave w: queries
// (w&3)*32..+31, keys (w>>2)*64..+63 of each 128-key tile. 16 iters,
// one barrier/iter, K/Vt double-buffered (64KB). Partial O/l summed across
// the two key-halves at the end via conflict-free LDS ([reg][wave][lane]).
// ---------------------------------------------------------------------------
__global__ __launch_bounds__(512, 4) void attn_kernel(const unsigned short* __restrict__ Q,
                                                      const unsigned short* __restrict__ K,
                                                      const unsigned short* __restrict__ Vt,
                                                      unsigned short* __restrict__ Aout) {
  __shared__ unsigned short Ks[2][128 * 64];    // 32 KB
  __shared__ unsigned short Vts[2][64 * 128];   // 32 KB
  int t = threadIdx.x, w = t >> 6, l = t & 63;
  int m16 = l & 15, q = l >> 4;
  int wq = w & 3, kh = w >> 2;                  // query group / key half
  int qt = blockIdx.x, bh = blockIdx.y;
  const unsigned short* qbase = Q + (size_t)bh * 2048 * 64 + (size_t)qt * 128 * 64;
  const unsigned short* kbase = K + (size_t)bh * 2048 * 64;
  const unsigned short* vtbase = Vt + (size_t)bh * 64 * 2048;

  // Q fragments: qf[mt][ks] = Q[wq*32+mt*16+m16][ks*32+q*8 ..+7]
  bs8 qf[2][2];
#pragma unroll
  for (int mt = 0; mt < 2; ++mt)
#pragma unroll
    for (int ks = 0; ks < 2; ++ks)
      qf[mt][ks] = *(const bs8*)(qbase + (size_t)(wq * 32 + mt * 16 + m16) * 64 + ks * 32 + q * 8);

  stage_rows64_8w(&Ks[0][0], kbase, 64, w, l);
  stage_vt_8w(&Vts[0][0], vtbase, 0, w, l);
  __syncthreads();

  f32x4 minit = {-MBOUND, -MBOUND, -MBOUND, -MBOUND};
  f32x4 zero4 = {0.f, 0.f, 0.f, 0.f};
  f32x4 o[2][4];
  float lsum[2] = {0.f, 0.f};
#pragma unroll
  for (int mt = 0; mt < 2; ++mt)
#pragma unroll
    for (int nh = 0; nh < 4; ++nh) o[mt][nh] = zero4;

  int vsw = (m16 >> 3) & 1;   // half-chunk unswizzle bit for vf reads

  for (int kt = 0; kt < 16; ++kt) {
    int buf = kt & 1;
    if (kt < 15) {
      stage_rows64_8w(&Ks[buf ^ 1][0], kbase + (size_t)(kt + 1) * 128 * 64, 64, w, l);
      stage_vt_8w(&Vts[buf ^ 1][0], vtbase, (kt + 1) * 128, w, l);
    }
    const unsigned short* Kb = &Ks[buf][0];
    const unsigned short* Vb = &Vts[buf][0];

    // ---- S^T tiles over this wave's 64 keys: sAcc[mt][nt], nt 0..3
    f32x4 sAcc[2][4];
#pragma unroll
    for (int mt = 0; mt < 2; ++mt)
#pragma unroll
      for (int nt = 0; nt < 4; ++nt) sAcc[mt][nt] = minit;
#pragma unroll
    for (int ks = 0; ks < 2; ++ks) {
      bs8 kf[4];
#pragma unroll
      for (int nt = 0; nt < 4; ++nt) {
        int row = kh * 64 + nt * 16 + m16;
        int c = ks * 4 + q;
        kf[nt] = *(const bs8*)&Kb[row * 64 + ((c ^ (row & 7)) * 8)];
      }
#pragma unroll
      for (int nt = 0; nt < 4; ++nt)
#pragma unroll
        for (int mt = 0; mt < 2; ++mt)
          sAcc[mt][nt] = __builtin_amdgcn_mfma_f32_16x16x32_bf16(kf[nt], qf[mt][ks],
                                                                 sAcc[mt][nt], 0, 0, 0);
    }

    // ---- p = exp2(s - 24), lane-local partial sums
#pragma unroll
    for (int mt = 0; mt < 2; ++mt) {
      float rs = 0.f;
#pragma unroll
      for (int nt = 0; nt < 4; ++nt)
#pragma unroll
        for (int r = 0; r < 4; ++r) {
          float p = __builtin_amdgcn_exp2f(sAcc[mt][nt][r]);
          sAcc[mt][nt][r] = p;
          rs += p;
        }
      lsum[mt] += rs;
    }

    // ---- partial O^T += V^T(key half) . P, straight from registers
#pragma unroll
    for (int nt = 0; nt < 4; ++nt) {
      bs4 vf[4];
#pragma unroll
      for (int nh = 0; nh < 4; ++nh) {
        int vrow = nh * 16 + m16;
        int chunk = kh * 8 + nt * 2 + (q >> 1);
        int within = ((q & 1) ^ vsw) * 4;          // matches Vt half-chunk swap
        vf[nh] = *(const bs4*)&Vb[vrow * 128 + ((chunk ^ (vrow & 15)) * 8) + within];
      }
#pragma unroll
      for (int mt = 0; mt < 2; ++mt) {
        union { bs4 v; unsigned int u[2]; } pf;
        pf.u[0] = pkbf2(sAcc[mt][nt][0], sAcc[mt][nt][1]);
        pf.u[1] = pkbf2(sAcc[mt][nt][2], sAcc[mt][nt][3]);
#pragma unroll
        for (int nh = 0; nh < 4; ++nh)
          o[mt][nh] = MFMA16K16(vf[nh], pf.v, o[mt][nh]);
      }
    }
    __syncthreads();
  }

  // ---- cross-key-half combine. Layout [reg][wave][lane]: lane stride 16B
  // for f32x4 -> conflict-free. Waves 4-7 publish, waves 0-3 add + write.
  float* ored = (float*)&Ks[0][0];    // 8 regs * 256 threads * 4 = 32 KB
  float* lred = (float*)&Vts[0][0];   // 2 * 256 floats = 2 KB
  if (w >= 4) {
#pragma unroll
    for (int mt = 0; mt < 2; ++mt)
#pragma unroll
      for (int nh = 0; nh < 4; ++nh)
        *(f32x4*)&ored[((mt * 4 + nh) * 256 + wq * 64 + l) * 4] = o[mt][nh];
    lred[0 * 256 + wq * 64 + l] = lsum[0];
    lred[1 * 256 + wq * 64 + l] = lsum[1];
  }
  __syncthreads();
  if (w < 4) {
#pragma unroll
    for (int mt = 0; mt < 2; ++mt)
#pragma unroll
      for (int nh = 0; nh < 4; ++nh) {
        f32x4 part = *(const f32x4*)&ored[((mt * 4 + nh) * 256 + wq * 64 + l) * 4];
#pragma unroll
        for (int r = 0; r < 4; ++r) o[mt][nh][r] += part[r];
      }
    lsum[0] += lred[0 * 256 + wq * 64 + l];
    lsum[1] += lred[1 * 256 + wq * 64 + l];

    int b = bh >> 4, h = bh & 15;
#pragma unroll
    for (int mt = 0; mt < 2; ++mt) {
      float l0 = lsum[mt];
      l0 += __shfl_xor(l0, 16);
      l0 += __shfl_xor(l0, 32);
      float inv = 1.0f / l0;
      int s = qt * 128 + wq * 32 + mt * 16 + m16;
#pragma unroll
      for (int nh = 0; nh < 4; ++nh)
#pragma unroll
        for (int r = 0; r < 4; ++r) {
          int hd = nh * 16 + q * 4 + r;
          Aout[((size_t)(b * 2048 + s)) * 1024 + h * 64 + hd] = f2bf(o[mt][nh][r] * inv);
        }
    }
  }
}

// ---------------------------------------------------------------------------
extern "C" void kernel_launch(void* const* d_in, const int* in_sizes, int n_in,
                              void* d_out, int out_size, void* d_ws, size_t ws_size,
                              hipStream_t stream) {
  const float* x     = (const float*)d_in[0];   // [2,2048,1024]
  const float* w_qkv = (const float*)d_in[1];   // [1024,3072]
  const float* b_qkv = (const float*)d_in[2];   // [3072]
  const float* w_out = (const float*)d_in[3];   // [1024,1024]
  const float* b_out = (const float*)d_in[4];   // [1024]
  float* out = (float*)d_out;                   // [2,2048,1024] fp32

  char* ws = (char*)d_ws;                       // needs 48 MB
  unsigned short* xb    = (unsigned short*)(ws);                     // 8 MB
  unsigned short* wt1   = (unsigned short*)(ws + (8u << 20));        // 6 MB
  unsigned short* wt2   = (unsigned short*)(ws + (14u << 20));       // 2 MB
  unsigned short* qb    = (unsigned short*)(ws + (16u << 20));       // 8 MB
  unsigned short* kb    = (unsigned short*)(ws + (24u << 20));       // 8 MB
  unsigned short* vtb   = (unsigned short*)(ws + (32u << 20));       // 8 MB
  unsigned short* attnb = (unsigned short*)(ws + (40u << 20));       // 8 MB

  prep_kernel<<<3072, 256, 0, stream>>>(x, xb, w_qkv, wt1, w_out, wt2);
  gemm_qkv_kernel<<<dim3(24, 32), 256, 0, stream>>>(xb, wt1, b_qkv, qb, kb, vtb);
  attn_kernel<<<dim3(16, 32), 512, 0, stream>>>(qb, kb, vtb, attnb);
  gemm_out_kernel<<<dim3(8, 64), 256, 0, stream>>>(attnb, wt2, b_out, out);
}